// Round 6
// baseline (284.115 us; speedup 1.0000x reference)
//
#include <hip/hip_runtime.h>
#include <hip/hip_bf16.h>
#include <stdint.h>

#define EPSF 1e-5f

typedef __attribute__((ext_vector_type(4))) int i32x4;
typedef __attribute__((ext_vector_type(16))) char c8x16;

__device__ __forceinline__ void gld_lds16(const void* g, void* l) {
  __builtin_amdgcn_global_load_lds((const __attribute__((address_space(1))) void*)g,
                                   (__attribute__((address_space(3))) void*)l, 16, 0, 0);
}

// ---------------- prep: binarize all 3 hidden weights f32 -> i8 [1024][1024], zero-pad ----------------
// blockIdx.y: 0 -> W0 (Ksrc=784), 1 -> Wh[0], 2 -> Wh[1] (Ksrc=1024). dst regions contiguous 1 MiB apart.
__global__ void k_binW(const float* __restrict__ W0, const float* __restrict__ Wh,
                       char* __restrict__ dstbase) {
  const int y = blockIdx.y;
  const float* src = (y == 0) ? W0 : (Wh + (size_t)(y - 1) * 1048576);
  const int Ksrc = (y == 0) ? 784 : 1024;
  char* dst = dstbase + (size_t)y * 1048576;
  int t = blockIdx.x * 256 + threadIdx.x;  // 65536 threads, 16 i8 each
  int c = t & 63;
  int n = t >> 6;
  int kc = Ksrc >> 4;  // 49 or 64
  c8x16 o;
  if (c < kc) {
    const float* p = src + (size_t)n * Ksrc + c * 16;
#pragma unroll
    for (int e = 0; e < 16; ++e) o[e] = (p[e] >= 0.0f) ? (char)1 : (char)-1;
  } else {
    o = (c8x16)0;
  }
  *(c8x16*)(dst + (size_t)t * 16) = o;
}

// ---------------- input binarize: x [65536 x 784] f32 -> X [65536 x 1024] i8 +-1, pad 0 ----------------
// sign(2x-1) == (x >= 0.5) exactly
__global__ void k_binX(const float* __restrict__ x, char* __restrict__ X) {
  size_t t = (size_t)blockIdx.x * 256 + threadIdx.x;  // 65536*64 threads
  int c = (int)(t & 63);
  size_t b = t >> 6;
  c8x16 o;
  if (c < 49) {  // 784 = 49*16
    const float* p = x + b * 784 + c * 16;
#pragma unroll
    for (int e = 0; e < 16; ++e) o[e] = (p[e] >= 0.5f) ? (char)1 : (char)-1;
  } else {
    o = (c8x16)0;
  }
  *(c8x16*)(X + b * 1024 + c * 16) = o;
}

// ---------------- small prep: inv_std (exact numpy f32 rounding) + binarized WL [16][1024] i8 ----------------
__global__ void k_prep(const float* __restrict__ bn_gamma, const float* __restrict__ bn_var,
                       const float* __restrict__ bnL_gamma, const float* __restrict__ bnL_var,
                       const float* __restrict__ WL,
                       float* __restrict__ invstd3, float* __restrict__ invstdL,
                       char* __restrict__ WLb) {
  int j = threadIdx.x;  // 1024
#pragma unroll
  for (int i = 0; i < 3; ++i) {
    int idx = i * 1024 + j;
    invstd3[idx] = __fdiv_rn(bn_gamma[idx], __fsqrt_rn(__fadd_rn(bn_var[idx], EPSF)));
  }
  if (j < 10) invstdL[j] = __fdiv_rn(bnL_gamma[j], __fsqrt_rn(__fadd_rn(bnL_var[j], EPSF)));
#pragma unroll
  for (int r = 0; r < 16; ++r) {
    char v = 0;
    if (r < 10) v = (WL[r * 1024 + j] >= 0.0f) ? (char)1 : (char)-1;
    WLb[r * 1024 + j] = v;
  }
}

// ---------------- main fused GEMM: C_bin = binarize(BN(A @ Bt^T)), i8 +-1, 16x16x64 MFMA ----------------
// 256x128 tile, 8 waves (4M x 2N), BK=128: per K-tile stage A 32KB + B 16KB for 256*128*128 MACs
// (87 MACs/byte). Same verified inner pattern as R5: LDS row-major [row][128B], linear dest for
// global_load_lds, global source chunk XOR-pre-swizzled within the 128B row, frag read slot =
// q ^ (row&7) -> 2-way-only bank aliasing. 32 MFMA + 16 ds_read_b128 per barrier interval per wave.
// XCD mapping: all 8 bn-blocks of one bm land on the same XCD.
__global__ __launch_bounds__(512, 2)
void gemm_bin(const char* __restrict__ A, const char* __restrict__ Bt,
              char* __restrict__ Cb,
              const float* __restrict__ mean, const float* __restrict__ beta,
              const float* __restrict__ invstd) {
  __shared__ char lds[49152];  // sA [0,32768): 256 rows x 128B; sB [32768,49152): 128 rows x 128B
  const int tid = threadIdx.x;   // 0..511
  const int lane = tid & 63;
  const int wave = tid >> 6;     // 0..7
  const int d = blockIdx.x;      // 0..2047
  const int xcd = d & 7;
  const int idx = d >> 3;        // 0..255
  const int bm = xcd * 32 + (idx >> 3);  // 0..255
  const int bn = idx & 7;
  const int wm = wave >> 1, wn = wave & 1;  // wm 0..3, wn 0..1
  const int l15 = lane & 15, lq = lane >> 4;

  // staging: thread t -> row srow = t>>3 (+64 per instr i), chunk (t&7)^(srow&7) (row&7 invariant in i);
  // LDS dest = instr i*8192 + wave*1024 + lane*16 (linear slot S = i*512 + t)
  const int srow = tid >> 3;  // 0..63
  const int schunk = ((tid & 7) ^ (srow & 7)) << 4;
  const char* gA = A + (size_t)(bm * 256 + srow) * 1024 + schunk;
  const char* gB = Bt + (size_t)(bn * 128 + srow) * 1024 + schunk;
  const int lwoff = (tid & ~63) * 16;  // wave-uniform; HW adds lane*16

  i32x4 acc[4][4];
#pragma unroll
  for (int m = 0; m < 4; ++m)
#pragma unroll
    for (int n = 0; n < 4; ++n) acc[m][n] = (i32x4)0;

  for (int k0 = 0; k0 < 1024; k0 += 128) {
#pragma unroll
    for (int i = 0; i < 4; ++i)  // A: 4 x 64 rows
      gld_lds16(gA + k0 + i * 65536, lds + lwoff + i * 8192);
#pragma unroll
    for (int i = 0; i < 2; ++i)  // B: 2 x 64 rows
      gld_lds16(gB + k0 + i * 65536, lds + 32768 + lwoff + i * 8192);
    __syncthreads();
#pragma unroll
    for (int s = 0; s < 2; ++s) {
      const int slot = (((s << 2) + lq) ^ (l15 & 7)) << 4;
      i32x4 af[4], bf[4];
#pragma unroll
      for (int m = 0; m < 4; ++m)
        af[m] = *(const i32x4*)(lds + (wm * 64 + m * 16 + l15) * 128 + slot);
#pragma unroll
      for (int n = 0; n < 4; ++n)
        bf[n] = *(const i32x4*)(lds + 32768 + (wn * 64 + n * 16 + l15) * 128 + slot);
#pragma unroll
      for (int m = 0; m < 4; ++m)
#pragma unroll
        for (int n = 0; n < 4; ++n)
          acc[m][n] = __builtin_amdgcn_mfma_i32_16x16x64_i8(af[m], bf[n], acc[m][n], 0, 0, 0);
    }
    __syncthreads();
  }

  // epilogue: exact int -> f32, BN with np-f32 rounding (no FMA), binarize to i8
  // C/D map (16x16): col = lane&15, row = (lane>>4)*4 + reg
  const int r0 = bm * 256 + wm * 64 + (lq << 2);
  const int c0 = bn * 128 + wn * 64 + l15;
#pragma unroll
  for (int n = 0; n < 4; ++n) {
    const int col = c0 + n * 16;
    const float mu = mean[col], is = invstd[col], be = beta[col];
#pragma unroll
    for (int m = 0; m < 4; ++m) {
#pragma unroll
      for (int j = 0; j < 4; ++j) {
        const int row = r0 + m * 16 + j;
        float y = __fadd_rn(__fmul_rn(__fsub_rn((float)acc[m][n][j], mu), is), be);
        Cb[(size_t)row * 1024 + col] = (y >= 0.0f) ? (char)1 : (char)-1;
      }
    }
  }
}

// ---------------- final layer: out[65536][10] = BN(A @ WLb^T), fp32 out, i8 inputs ----------------
// (verified in R2 -- unchanged)
__global__ __launch_bounds__(256, 2)
void gemm_fin(const char* __restrict__ A, const char* __restrict__ BtL,
              float* __restrict__ out,
              const float* __restrict__ meanL, const float* __restrict__ betaL,
              const float* __restrict__ invstdL) {
  constexpr int K = 1024;
  __shared__ char sA[128 * 64];
  __shared__ char sB[16 * 64];
  const int tid = threadIdx.x;
  const int lane = tid & 63;
  const int wave = tid >> 6;
  const int bm = blockIdx.x;

  const int sr = tid >> 2;
  const int csrc = ((tid & 3) ^ (sr & 3)) << 4;
  const char* gA = A + (size_t)(bm * 128 + sr) * K + csrc;
  const char* gB = BtL + (size_t)sr * K + csrc;
  char* lA = sA + (tid & ~63) * 16;
  char* lB = sB;

  const int slot = ((lane >> 4) ^ (lane & 3)) << 4;
  const char* rA = sA + (wave * 32 + (lane & 15)) * 64 + slot;
  const char* rB = sB + (lane & 15) * 64 + slot;

  i32x4 acc0 = (i32x4)0, acc1 = (i32x4)0;

  for (int k0 = 0; k0 < K; k0 += 64) {
    gld_lds16(gA, lA);
    gld_lds16(gA + (size_t)64 * K, lA + 4096);
    if (tid < 64) gld_lds16(gB, lB);
    gA += 64;
    gB += 64;
    __syncthreads();
    i32x4 af0 = *(const i32x4*)(rA);
    i32x4 af1 = *(const i32x4*)(rA + 16 * 64);
    i32x4 b0 = *(const i32x4*)(rB);
    acc0 = __builtin_amdgcn_mfma_i32_16x16x64_i8(af0, b0, acc0, 0, 0, 0);
    acc1 = __builtin_amdgcn_mfma_i32_16x16x64_i8(af1, b0, acc1, 0, 0, 0);
    __syncthreads();
  }

  const int col = lane & 15;
  if (col < 10) {
    const float mu = meanL[col], is = invstdL[col], be = betaL[col];
    const int r0 = bm * 128 + wave * 32 + ((lane >> 4) << 2);
#pragma unroll
    for (int m = 0; m < 2; ++m) {
      const i32x4 a = (m == 0) ? acc0 : acc1;
#pragma unroll
      for (int j = 0; j < 4; ++j) {
        const int row = r0 + m * 16 + j;
        out[(size_t)row * 10 + col] = __fadd_rn(__fmul_rn(__fsub_rn((float)a[j], mu), is), be);
      }
    }
  }
}

extern "C" void kernel_launch(void* const* d_in, const int* in_sizes, int n_in,
                              void* d_out, int out_size, void* d_ws, size_t ws_size,
                              hipStream_t stream) {
  const float* x = (const float*)d_in[0];
  const float* W0 = (const float*)d_in[1];
  const float* Wh = (const float*)d_in[2];
  const float* WL = (const float*)d_in[3];
  const float* bn_gamma = (const float*)d_in[4];
  const float* bn_beta = (const float*)d_in[5];
  const float* bn_mean = (const float*)d_in[6];
  const float* bn_var = (const float*)d_in[7];
  const float* bnL_gamma = (const float*)d_in[8];
  const float* bnL_beta = (const float*)d_in[9];
  const float* bnL_mean = (const float*)d_in[10];
  const float* bnL_var = (const float*)d_in[11];
  float* out = (float*)d_out;

  // workspace layout (~140 MB)
  char* ws = (char*)d_ws;
  char* X0 = ws;                                   // 67108864 B
  char* X1 = ws + 67108864;                        // 67108864 B
  char* wbase = ws + 134217728;                    // W0b/Wh0b/Wh1b contiguous 1 MiB each
  char* W0b = wbase;
  char* Wh0b = wbase + 1048576;
  char* Wh1b = wbase + 2 * 1048576;
  char* WLb = wbase + 3 * 1048576;                 // 16 KiB
  float* invstd3 = (float*)(wbase + 3 * 1048576 + 16384);  // 12 KiB
  float* invstdL = invstd3 + 3 * 1024;

  hipLaunchKernelGGL(k_prep, dim3(1), dim3(1024), 0, stream,
                     bn_gamma, bn_var, bnL_gamma, bnL_var, WL, invstd3, invstdL, WLb);
  hipLaunchKernelGGL(k_binW, dim3(256, 3), dim3(256), 0, stream, W0, Wh, wbase);
  hipLaunchKernelGGL(k_binX, dim3(16384), dim3(256), 0, stream, x, X0);

  hipLaunchKernelGGL(gemm_bin, dim3(2048), dim3(512), 0, stream, X0, W0b, X1,
                     bn_mean, bn_beta, invstd3);
  hipLaunchKernelGGL(gemm_bin, dim3(2048), dim3(512), 0, stream, X1, Wh0b, X0,
                     bn_mean + 1024, bn_beta + 1024, invstd3 + 1024);
  hipLaunchKernelGGL(gemm_bin, dim3(2048), dim3(512), 0, stream, X0, Wh1b, X1,
                     bn_mean + 2048, bn_beta + 2048, invstd3 + 2048);
  hipLaunchKernelGGL(gemm_fin, dim3(512), dim3(256), 0, stream, X1, WLb, out,
                     bnL_mean, bnL_beta, invstdL);
}